// Round 2
// baseline (416.001 us; speedup 1.0000x reference)
//
#include <hip/hip_runtime.h>

// DownSample fused: gather(knn) -> LayerNorm(C=128) -> Linear(128->256, bf16 MFMA) -> maxpool(k=16)
// Outputs concatenated: out[m,256] f32 | n_p[m,3] f32 | n_o[4] as f32
//
// R2 design: barrier-free. Each 256-thread block = 4 independent waves; wave w owns
// output cols [w*64, w*64+64). All 4 waves redundantly gather the same query's
// 16x128 A-tile straight into registers in MFMA A-fragment layout (L1 absorbs the
// redundancy). LayerNorm affine folded into W (W' = W*nw, bias c = nb@W^T added
// after maxpool). No LDS, no __syncthreads in the hot loop.

#define C_IN   128
#define C_OUT  256
#define KNN    16
#define LN_EPS 1e-5f

typedef __attribute__((ext_vector_type(8))) short  short8;
typedef __attribute__((ext_vector_type(8))) __bf16 bf16x8;
typedef __attribute__((ext_vector_type(4))) float  f32x4;

__device__ __forceinline__ short f2bf_bits(float f) {
    unsigned u = __float_as_uint(f);
    u += 0x7fffu + ((u >> 16) & 1u);   // round-to-nearest-even
    return (short)(u >> 16);
}

__global__ __launch_bounds__(256) void fused_kernel(
    const float* __restrict__ x, const int* __restrict__ knn,
    const float* __restrict__ nw, const float* __restrict__ nb,
    const float* __restrict__ W,
    const float* __restrict__ n_p, const int* __restrict__ n_o,
    float* __restrict__ out, float* __restrict__ out_np, float* __restrict__ out_no,
    int mq, int npcnt)
{
    const int tid  = threadIdx.x;
    const int lane = tid & 63;
    const int wave = tid >> 6;          // wave w owns out cols [w*64, w*64+64)
    const int m16  = lane & 15;         // A-row / B-col / D-col index
    const int qd   = lane >> 4;         // quad within wave

    // ---- Preamble: build B fragments W'[n][k] = W[n][k]*nw[k] (bf16) and
    //      per-col bias c[n] = sum_k nb[k]*W[n][k]. Register-resident all kernel.
    // b_frag layout for mfma_f32_16x16x32_bf16: lane holds B[k=k0+j][n=lane&15]
    short8 bfrag[4][4];                 // [n-tile][k-step]
    float  cpart[4] = {0.f, 0.f, 0.f, 0.f};
    #pragma unroll
    for (int s = 0; s < 4; ++s) {
        const int k0 = s * 32 + qd * 8;
        const float4 a0 = *(const float4*)(nw + k0);
        const float4 a1 = *(const float4*)(nw + k0 + 4);
        const float4 c0 = *(const float4*)(nb + k0);
        const float4 c1 = *(const float4*)(nb + k0 + 4);
        const float nwv[8] = {a0.x,a0.y,a0.z,a0.w,a1.x,a1.y,a1.z,a1.w};
        const float nbv[8] = {c0.x,c0.y,c0.z,c0.w,c1.x,c1.y,c1.z,c1.w};
        #pragma unroll
        for (int t = 0; t < 4; ++t) {
            const int n = wave * 64 + t * 16 + m16;
            const float4* wp = (const float4*)(W + n * C_IN + k0);
            const float4 w0 = wp[0], w1 = wp[1];
            const float wvv[8] = {w0.x,w0.y,w0.z,w0.w,w1.x,w1.y,w1.z,w1.w};
            short8 b;
            #pragma unroll
            for (int j = 0; j < 8; ++j) {
                b[j] = f2bf_bits(wvv[j] * nwv[j]);
                cpart[t] += nbv[j] * wvv[j];
            }
            bfrag[t][s] = b;
        }
    }
    #pragma unroll
    for (int t = 0; t < 4; ++t) {        // full c over the 128 channels
        cpart[t] += __shfl_xor(cpart[t], 16);
        cpart[t] += __shfl_xor(cpart[t], 32);
    }
    const float cbias = (qd == 0) ? cpart[0] : (qd == 1) ? cpart[1]
                      : (qd == 2) ? cpart[2] : cpart[3];

    for (int q = blockIdx.x; q < mq; q += gridDim.x) {
        // ---- gather: lane loads row knn[q][m16], channels {s*32+qd*8 .. +8} ----
        const int idx = knn[q * KNN + m16];
        const float* xr = x + (long long)idx * C_IN;
        float vals[32];
        #pragma unroll
        for (int s = 0; s < 4; ++s) {
            const float4 v0 = *(const float4*)(xr + s * 32 + qd * 8);
            const float4 v1 = *(const float4*)(xr + s * 32 + qd * 8 + 4);
            vals[s*8+0]=v0.x; vals[s*8+1]=v0.y; vals[s*8+2]=v0.z; vals[s*8+3]=v0.w;
            vals[s*8+4]=v1.x; vals[s*8+5]=v1.y; vals[s*8+6]=v1.z; vals[s*8+7]=v1.w;
        }

        // ---- LayerNorm stats: row m16 is spread over the 4 qd-lanes ----
        float s1 = 0.f, s2 = 0.f;
        #pragma unroll
        for (int j = 0; j < 32; ++j) { s1 += vals[j]; s2 += vals[j] * vals[j]; }
        s1 += __shfl_xor(s1, 16); s1 += __shfl_xor(s1, 32);
        s2 += __shfl_xor(s2, 16); s2 += __shfl_xor(s2, 32);
        const float mu   = s1 * (1.f / 128.f);
        const float var  = s2 * (1.f / 128.f) - mu * mu;
        const float rstd = rsqrtf(var + LN_EPS);

        // ---- normalize -> bf16 A-frags -> MFMA ----
        f32x4 acc[4] = {{0,0,0,0},{0,0,0,0},{0,0,0,0},{0,0,0,0}};
        #pragma unroll
        for (int s = 0; s < 4; ++s) {
            short8 a;
            #pragma unroll
            for (int j = 0; j < 8; ++j)
                a[j] = f2bf_bits((vals[s*8+j] - mu) * rstd);
            const bf16x8 av = __builtin_bit_cast(bf16x8, a);
            #pragma unroll
            for (int t = 0; t < 4; ++t)
                acc[t] = __builtin_amdgcn_mfma_f32_16x16x32_bf16(
                    av, __builtin_bit_cast(bf16x8, bfrag[t][s]), acc[t], 0, 0, 0);
        }

        // ---- maxpool over 16 rows (C layout: col=lane&15, row=qd*4+reg) ----
        float r[4];
        #pragma unroll
        for (int t = 0; t < 4; ++t) {
            float v = fmaxf(fmaxf(acc[t][0], acc[t][1]), fmaxf(acc[t][2], acc[t][3]));
            v = fmaxf(v, __shfl_xor(v, 16));
            v = fmaxf(v, __shfl_xor(v, 32));
            r[t] = v;
        }
        const float vout = ((qd == 0) ? r[0] : (qd == 1) ? r[1]
                          : (qd == 2) ? r[2] : r[3]) + cbias;
        out[q * C_OUT + wave * 64 + lane] = vout;   // coalesced 256 B per wave
    }

    // ---- passthrough outputs (merged to avoid a second dispatch) ----
    const int gtid = blockIdx.x * 256 + tid;
    const int gstr = gridDim.x * 256;
    for (int i = gtid; i < npcnt; i += gstr) out_np[i] = n_p[i];
    if (gtid < 4) out_no[gtid] = (float)n_o[gtid];
}

extern "C" void kernel_launch(void* const* d_in, const int* in_sizes, int n_in,
                              void* d_out, int out_size, void* d_ws, size_t ws_size,
                              hipStream_t stream)
{
    const float* x   = (const float*)d_in[1];
    const float* n_p = (const float*)d_in[3];
    const int*   knn = (const int*)  d_in[4];
    const int*   n_o = (const int*)  d_in[5];
    const float* nw  = (const float*)d_in[6];
    const float* nb  = (const float*)d_in[7];
    const float* W   = (const float*)d_in[8];
    float* out = (float*)d_out;

    const int mq    = in_sizes[4] / KNN;   // 50000
    const int npcnt = in_sizes[3];         // 150000
    float* out_np = out + (size_t)mq * C_OUT;
    float* out_no = out_np + npcnt;

    hipLaunchKernelGGL(fused_kernel, dim3(1024), dim3(256), 0, stream,
                       x, knn, nw, nb, W, n_p, n_o, out, out_np, out_no, mq, npcnt);
}

// Round 3
// 321.687 us; speedup vs baseline: 1.2932x; 1.2932x over previous
//
#include <hip/hip_runtime.h>

// DownSample fused: gather(knn) -> LayerNorm(C=128) -> Linear(128->256, bf16 MFMA) -> maxpool(k=16)
// Outputs concatenated: out[m,256] f32 | n_p[m,3] f32 | n_o[4] as f32
//
// R3: cooperative coalesced staging (R1) + software pipeline:
//  - batch BQ=2 queries/iter (32 rows), double-buffered LDS, ONE barrier/iter
//  - next batch's gather issued right after the barrier (in flight during MFMA)
//  - knn indices prefetched 2 iterations ahead (break idx->gather dependency)
//  - XOR-swizzled LDS blocks: conflict-free ds_read_b128, 2-way (free) writes
//  - W' = W*nw bf16 register-resident; bias c = nb.W added after maxpool

#define C_IN   128
#define C_OUT  256
#define KNN    16
#define LN_EPS 1e-5f
#define BQ     2
#define ROWS   (BQ * KNN)     // 32
#define NBLK   1024

typedef __attribute__((ext_vector_type(8))) short  short8;
typedef __attribute__((ext_vector_type(4))) short  short4_t;
typedef __attribute__((ext_vector_type(8))) __bf16 bf16x8;
typedef __attribute__((ext_vector_type(4))) float  f32x4;

__device__ __forceinline__ short f2bf_bits(float f) {
    unsigned u = __float_as_uint(f);
    u += 0x7fffu + ((u >> 16) & 1u);   // round-to-nearest-even
    return (short)(u >> 16);
}

__global__ __launch_bounds__(256, 4) void fused_kernel(
    const float* __restrict__ x, const int* __restrict__ knn,
    const float* __restrict__ nw, const float* __restrict__ nb,
    const float* __restrict__ W,
    const float* __restrict__ n_p, const int* __restrict__ n_o,
    float* __restrict__ out, float* __restrict__ out_np, float* __restrict__ out_no,
    int mq, int npcnt)
{
    // 2 buffers x 32 rows x 128 bf16, 16B blocks XOR-swizzled by (row&15). 16 KB.
    __shared__ __align__(16) short Ash[2 * ROWS * C_IN];

    const int tid  = threadIdx.x;
    const int lane = tid & 63;
    const int wave = tid >> 6;          // wave w owns out cols [w*64, w*64+64)
    const int m16  = lane & 15;
    const int qd   = lane >> 4;

    // ---- preamble: B fragments W'[n][k] = W[n][k]*nw[k] (bf16); c[n] = sum_k nb[k]W[n][k]
    short8 bfrag[4][4];                 // [n-tile][k-step]
    float  cpart[4] = {0.f, 0.f, 0.f, 0.f};
    #pragma unroll
    for (int s = 0; s < 4; ++s) {
        const int k0 = s * 32 + qd * 8;
        const float4 a0 = *(const float4*)(nw + k0);
        const float4 a1 = *(const float4*)(nw + k0 + 4);
        const float4 c0 = *(const float4*)(nb + k0);
        const float4 c1 = *(const float4*)(nb + k0 + 4);
        const float nwv[8] = {a0.x,a0.y,a0.z,a0.w,a1.x,a1.y,a1.z,a1.w};
        const float nbv[8] = {c0.x,c0.y,c0.z,c0.w,c1.x,c1.y,c1.z,c1.w};
        #pragma unroll
        for (int t = 0; t < 4; ++t) {
            const int n = wave * 64 + t * 16 + m16;
            const float4* wp = (const float4*)(W + n * C_IN + k0);
            const float4 w0 = wp[0], w1 = wp[1];
            const float wvv[8] = {w0.x,w0.y,w0.z,w0.w,w1.x,w1.y,w1.z,w1.w};
            short8 b;
            #pragma unroll
            for (int j = 0; j < 8; ++j) {
                b[j] = f2bf_bits(wvv[j] * nwv[j]);
                cpart[t] += nbv[j] * wvv[j];
            }
            bfrag[t][s] = b;
        }
    }
    #pragma unroll
    for (int t = 0; t < 4; ++t) {
        cpart[t] += __shfl_xor(cpart[t], 16);
        cpart[t] += __shfl_xor(cpart[t], 32);
    }
    const float cbias = (qd == 0) ? cpart[0] : (qd == 1) ? cpart[1]
                      : (qd == 2) ? cpart[2] : cpart[3];

    // ---- staging role: thread = (row sr, chunk sc); channels {sc*4 + t*32 + u} ----
    const int sr = tid >> 3;            // 0..31
    const int sc = tid & 7;             // 0..7

    const int nbat = (mq + BQ - 1) / BQ;
    const int g = gridDim.x;

    // prime the pipeline: gather batch blockIdx.x; idx for batch +g
    int bat = blockIdx.x;
    float4 pf[4];
    int idxn;
    {
        const int id0 = knn[bat * ROWS + sr];
        const float* xr = x + (long long)id0 * C_IN + sc * 4;
        #pragma unroll
        for (int t = 0; t < 4; ++t) pf[t] = *(const float4*)(xr + t * 32);
        const int b1 = (bat + g < nbat) ? (bat + g) : bat;
        idxn = knn[b1 * ROWS + sr];
    }

    int buf = 0;
    for (; bat < nbat; bat += g) {
        // ---- LayerNorm on prefetched rows -> bf16 -> swizzled LDS ----
        float s1 = 0.f, s2 = 0.f;
        #pragma unroll
        for (int t = 0; t < 4; ++t) {
            s1 += pf[t].x + pf[t].y + pf[t].z + pf[t].w;
            s2 += pf[t].x*pf[t].x + pf[t].y*pf[t].y + pf[t].z*pf[t].z + pf[t].w*pf[t].w;
        }
        #pragma unroll
        for (int off = 1; off < 8; off <<= 1) {
            s1 += __shfl_xor(s1, off);
            s2 += __shfl_xor(s2, off);
        }
        const float mu   = s1 * (1.f / 128.f);
        const float rstd = rsqrtf(s2 * (1.f / 128.f) - mu * mu + LN_EPS);
        #pragma unroll
        for (int t = 0; t < 4; ++t) {
            short4_t hb;
            hb[0] = f2bf_bits((pf[t].x - mu) * rstd);
            hb[1] = f2bf_bits((pf[t].y - mu) * rstd);
            hb[2] = f2bf_bits((pf[t].z - mu) * rstd);
            hb[3] = f2bf_bits((pf[t].w - mu) * rstd);
            const int pb = ((sc >> 1) + 4 * t) ^ (sr & 15);     // 16B-block swizzle
            *(short4_t*)&Ash[buf * 4096 + sr * 128 + pb * 8 + (sc & 1) * 4] = hb;
        }
        __syncthreads();

        // ---- issue next batch's gather NOW (in flight during MFMA below) ----
        if (bat + g < nbat) {
            const float* xr = x + (long long)idxn * C_IN + sc * 4;
            #pragma unroll
            for (int t = 0; t < 4; ++t) pf[t] = *(const float4*)(xr + t * 32);
            const int b2 = (bat + 2 * g < nbat) ? (bat + 2 * g) : (bat + g);
            idxn = knn[b2 * ROWS + sr];
        }

        // ---- MFMA + maxpool + store for the 2 queries of this batch ----
        #pragma unroll
        for (int ql = 0; ql < BQ; ++ql) {
            short8 afrag[4];
            #pragma unroll
            for (int s = 0; s < 4; ++s) {
                const int pb = (s * 4 + qd) ^ m16;
                afrag[s] = *(const short8*)&Ash[buf * 4096 + (ql * 16 + m16) * 128 + pb * 8];
            }
            f32x4 acc[4] = {{0,0,0,0},{0,0,0,0},{0,0,0,0},{0,0,0,0}};
            #pragma unroll
            for (int s = 0; s < 4; ++s) {
                const bf16x8 av = __builtin_bit_cast(bf16x8, afrag[s]);
                #pragma unroll
                for (int t = 0; t < 4; ++t)
                    acc[t] = __builtin_amdgcn_mfma_f32_16x16x32_bf16(
                        av, __builtin_bit_cast(bf16x8, bfrag[t][s]), acc[t], 0, 0, 0);
            }
            float r[4];
            #pragma unroll
            for (int t = 0; t < 4; ++t) {
                float v = fmaxf(fmaxf(acc[t][0], acc[t][1]), fmaxf(acc[t][2], acc[t][3]));
                v = fmaxf(v, __shfl_xor(v, 16));
                v = fmaxf(v, __shfl_xor(v, 32));
                r[t] = v;
            }
            const float vout = ((qd == 0) ? r[0] : (qd == 1) ? r[1]
                              : (qd == 2) ? r[2] : r[3]) + cbias;
            const int q = bat * BQ + ql;
            if (q < mq) out[q * C_OUT + wave * 64 + lane] = vout;
        }
        buf ^= 1;
    }

    // ---- passthrough outputs ----
    const int gtid = blockIdx.x * 256 + tid;
    const int gstr = g * 256;
    const int np4 = npcnt >> 2;
    for (int i = gtid; i < np4; i += gstr)
        ((float4*)out_np)[i] = ((const float4*)n_p)[i];
    for (int i = (np4 << 2) + gtid; i < npcnt; i += gstr) out_np[i] = n_p[i];
    if (gtid < 4) out_no[gtid] = (float)n_o[gtid];
}

extern "C" void kernel_launch(void* const* d_in, const int* in_sizes, int n_in,
                              void* d_out, int out_size, void* d_ws, size_t ws_size,
                              hipStream_t stream)
{
    const float* x   = (const float*)d_in[1];
    const float* n_p = (const float*)d_in[3];
    const int*   knn = (const int*)  d_in[4];
    const int*   n_o = (const int*)  d_in[5];
    const float* nw  = (const float*)d_in[6];
    const float* nb  = (const float*)d_in[7];
    const float* W   = (const float*)d_in[8];
    float* out = (float*)d_out;

    const int mq    = in_sizes[4] / KNN;   // 50000
    const int npcnt = in_sizes[3];         // 150000
    float* out_np = out + (size_t)mq * C_OUT;
    float* out_no = out_np + npcnt;

    hipLaunchKernelGGL(fused_kernel, dim3(NBLK), dim3(256), 0, stream,
                       x, knn, nw, nb, W, n_p, n_o, out, out_np, out_no, mq, npcnt);
}

// Round 4
// 252.474 us; speedup vs baseline: 1.6477x; 1.2741x over previous
//
#include <hip/hip_runtime.h>

// DownSample fused: gather(knn) -> LayerNorm(C=128) -> Linear(128->256, bf16 MFMA) -> maxpool(k=16)
// Outputs concatenated: out[m,256] f32 | n_p[m,3] f32 | n_o[4] as f32
//
// R4 = R3 pipeline with the register budget fixed: __launch_bounds__(256) only.
// R3's __launch_bounds__(256,4) forced 64 VGPRs -> scratch spills (WRITE_SIZE
// 50->207MB, FETCH +100MB). Structure unchanged:
//  - batch BQ=2 queries/iter (32 rows), double-buffered LDS, ONE barrier/iter
//  - next batch's gather issued right after the barrier (in flight during MFMA)
//  - knn indices prefetched 2 iterations ahead
//  - XOR-swizzled LDS 16B blocks: conflict-free ds_read_b128
//  - W' = W*nw bf16 register-resident; bias c = nb.W added after maxpool

#define C_IN   128
#define C_OUT  256
#define KNN    16
#define LN_EPS 1e-5f
#define BQ     2
#define ROWS   (BQ * KNN)     // 32
#define NBLK   1024

typedef __attribute__((ext_vector_type(8))) short  short8;
typedef __attribute__((ext_vector_type(4))) short  short4_t;
typedef __attribute__((ext_vector_type(8))) __bf16 bf16x8;
typedef __attribute__((ext_vector_type(4))) float  f32x4;

__device__ __forceinline__ short f2bf_bits(float f) {
    unsigned u = __float_as_uint(f);
    u += 0x7fffu + ((u >> 16) & 1u);   // round-to-nearest-even
    return (short)(u >> 16);
}

__global__ __launch_bounds__(256) void fused_kernel(
    const float* __restrict__ x, const int* __restrict__ knn,
    const float* __restrict__ nw, const float* __restrict__ nb,
    const float* __restrict__ W,
    const float* __restrict__ n_p, const int* __restrict__ n_o,
    float* __restrict__ out, float* __restrict__ out_np, float* __restrict__ out_no,
    int mq, int npcnt)
{
    // 2 buffers x 32 rows x 128 bf16, 16B blocks XOR-swizzled by (row&15). 16 KB.
    __shared__ __align__(16) short Ash[2 * ROWS * C_IN];

    const int tid  = threadIdx.x;
    const int lane = tid & 63;
    const int wave = tid >> 6;          // wave w owns out cols [w*64, w*64+64)
    const int m16  = lane & 15;
    const int qd   = lane >> 4;

    // ---- preamble: B fragments W'[n][k] = W[n][k]*nw[k] (bf16); c[n] = sum_k nb[k]W[n][k]
    short8 bfrag[4][4];                 // [n-tile][k-step]
    float  cpart[4] = {0.f, 0.f, 0.f, 0.f};
    #pragma unroll
    for (int s = 0; s < 4; ++s) {
        const int k0 = s * 32 + qd * 8;
        const float4 a0 = *(const float4*)(nw + k0);
        const float4 a1 = *(const float4*)(nw + k0 + 4);
        const float4 c0 = *(const float4*)(nb + k0);
        const float4 c1 = *(const float4*)(nb + k0 + 4);
        const float nwv[8] = {a0.x,a0.y,a0.z,a0.w,a1.x,a1.y,a1.z,a1.w};
        const float nbv[8] = {c0.x,c0.y,c0.z,c0.w,c1.x,c1.y,c1.z,c1.w};
        #pragma unroll
        for (int t = 0; t < 4; ++t) {
            const int n = wave * 64 + t * 16 + m16;
            const float4* wp = (const float4*)(W + n * C_IN + k0);
            const float4 w0 = wp[0], w1 = wp[1];
            const float wvv[8] = {w0.x,w0.y,w0.z,w0.w,w1.x,w1.y,w1.z,w1.w};
            short8 b;
            #pragma unroll
            for (int j = 0; j < 8; ++j) {
                b[j] = f2bf_bits(wvv[j] * nwv[j]);
                cpart[t] += nbv[j] * wvv[j];
            }
            bfrag[t][s] = b;
        }
    }
    #pragma unroll
    for (int t = 0; t < 4; ++t) {
        cpart[t] += __shfl_xor(cpart[t], 16);
        cpart[t] += __shfl_xor(cpart[t], 32);
    }
    const float cbias = (qd == 0) ? cpart[0] : (qd == 1) ? cpart[1]
                      : (qd == 2) ? cpart[2] : cpart[3];

    // ---- staging role: thread = (row sr, chunk sc); channels {sc*4 + t*32 + u} ----
    const int sr = tid >> 3;            // 0..31
    const int sc = tid & 7;             // 0..7

    const int nbat = (mq + BQ - 1) / BQ;
    const int g = gridDim.x;

    // prime the pipeline: gather batch blockIdx.x; idx for batch +g
    int bat = blockIdx.x;
    float4 pf[4];
    int idxn;
    {
        const int id0 = knn[bat * ROWS + sr];
        const float* xr = x + (long long)id0 * C_IN + sc * 4;
        #pragma unroll
        for (int t = 0; t < 4; ++t) pf[t] = *(const float4*)(xr + t * 32);
        const int b1 = (bat + g < nbat) ? (bat + g) : bat;
        idxn = knn[b1 * ROWS + sr];
    }

    int buf = 0;
    for (; bat < nbat; bat += g) {
        // ---- LayerNorm on prefetched rows -> bf16 -> swizzled LDS ----
        float s1 = 0.f, s2 = 0.f;
        #pragma unroll
        for (int t = 0; t < 4; ++t) {
            s1 += pf[t].x + pf[t].y + pf[t].z + pf[t].w;
            s2 += pf[t].x*pf[t].x + pf[t].y*pf[t].y + pf[t].z*pf[t].z + pf[t].w*pf[t].w;
        }
        #pragma unroll
        for (int off = 1; off < 8; off <<= 1) {
            s1 += __shfl_xor(s1, off);
            s2 += __shfl_xor(s2, off);
        }
        const float mu   = s1 * (1.f / 128.f);
        const float rstd = rsqrtf(s2 * (1.f / 128.f) - mu * mu + LN_EPS);
        #pragma unroll
        for (int t = 0; t < 4; ++t) {
            short4_t hb;
            hb[0] = f2bf_bits((pf[t].x - mu) * rstd);
            hb[1] = f2bf_bits((pf[t].y - mu) * rstd);
            hb[2] = f2bf_bits((pf[t].z - mu) * rstd);
            hb[3] = f2bf_bits((pf[t].w - mu) * rstd);
            const int pb = ((sc >> 1) + 4 * t) ^ (sr & 15);     // 16B-block swizzle
            *(short4_t*)&Ash[buf * 4096 + sr * 128 + pb * 8 + (sc & 1) * 4] = hb;
        }
        __syncthreads();

        // ---- issue next batch's gather NOW (in flight during MFMA below) ----
        if (bat + g < nbat) {
            const float* xr = x + (long long)idxn * C_IN + sc * 4;
            #pragma unroll
            for (int t = 0; t < 4; ++t) pf[t] = *(const float4*)(xr + t * 32);
            const int b2 = (bat + 2 * g < nbat) ? (bat + 2 * g) : (bat + g);
            idxn = knn[b2 * ROWS + sr];
        }

        // ---- MFMA + maxpool + store for the 2 queries of this batch ----
        #pragma unroll
        for (int ql = 0; ql < BQ; ++ql) {
            short8 afrag[4];
            #pragma unroll
            for (int s = 0; s < 4; ++s) {
                const int pb = (s * 4 + qd) ^ m16;
                afrag[s] = *(const short8*)&Ash[buf * 4096 + (ql * 16 + m16) * 128 + pb * 8];
            }
            f32x4 acc[4] = {{0,0,0,0},{0,0,0,0},{0,0,0,0},{0,0,0,0}};
            #pragma unroll
            for (int s = 0; s < 4; ++s) {
                const bf16x8 av = __builtin_bit_cast(bf16x8, afrag[s]);
                #pragma unroll
                for (int t = 0; t < 4; ++t)
                    acc[t] = __builtin_amdgcn_mfma_f32_16x16x32_bf16(
                        av, __builtin_bit_cast(bf16x8, bfrag[t][s]), acc[t], 0, 0, 0);
            }
            float r[4];
            #pragma unroll
            for (int t = 0; t < 4; ++t) {
                float v = fmaxf(fmaxf(acc[t][0], acc[t][1]), fmaxf(acc[t][2], acc[t][3]));
                v = fmaxf(v, __shfl_xor(v, 16));
                v = fmaxf(v, __shfl_xor(v, 32));
                r[t] = v;
            }
            const float vout = ((qd == 0) ? r[0] : (qd == 1) ? r[1]
                              : (qd == 2) ? r[2] : r[3]) + cbias;
            const int q = bat * BQ + ql;
            if (q < mq) out[q * C_OUT + wave * 64 + lane] = vout;
        }
        buf ^= 1;
    }

    // ---- passthrough outputs ----
    const int gtid = blockIdx.x * 256 + tid;
    const int gstr = g * 256;
    const int np4 = npcnt >> 2;
    for (int i = gtid; i < np4; i += gstr)
        ((float4*)out_np)[i] = ((const float4*)n_p)[i];
    for (int i = (np4 << 2) + gtid; i < npcnt; i += gstr) out_np[i] = n_p[i];
    if (gtid < 4) out_no[gtid] = (float)n_o[gtid];
}

extern "C" void kernel_launch(void* const* d_in, const int* in_sizes, int n_in,
                              void* d_out, int out_size, void* d_ws, size_t ws_size,
                              hipStream_t stream)
{
    const float* x   = (const float*)d_in[1];
    const float* n_p = (const float*)d_in[3];
    const int*   knn = (const int*)  d_in[4];
    const int*   n_o = (const int*)  d_in[5];
    const float* nw  = (const float*)d_in[6];
    const float* nb  = (const float*)d_in[7];
    const float* W   = (const float*)d_in[8];
    float* out = (float*)d_out;

    const int mq    = in_sizes[4] / KNN;   // 50000
    const int npcnt = in_sizes[3];         // 150000
    float* out_np = out + (size_t)mq * C_OUT;
    float* out_no = out_np + npcnt;

    hipLaunchKernelGGL(fused_kernel, dim3(NBLK), dim3(256), 0, stream,
                       x, knn, nw, nb, W, n_p, n_o, out, out_np, out_no, mq, npcnt);
}